// Round 1
// baseline (2824.052 us; speedup 1.0000x reference)
//
#include <hip/hip_runtime.h>
#include <math.h>

// SoftHd: soft Hausdorff distance, batched-pairwise.
// v1: (64,128,128) f32, sz1: (64,) int, v2: (64,128,128) f32, sz2: (64,) int
// out: (64,64) f32.
// out[b1,b2] = (sz1>0 ? sum_{j<sz2} min_{i<sz1} dist[i,j] : 0)
//            + (sz2>0 ? sum_{i<sz1} min_{j<sz2} dist[i,j] : 0)
// The reference's global-max fill never affects the output (it can't win a min
// against a valid distance, and fully-masked rows/cols are zeroed).

#define N1C 128
#define N2C 128
#define DC  128
#define KT  32
#define PITCH 33   // pitch 33: A-reads (4 rows/wave, stride 8*33%32=8) conflict-free;
                   // B-reads j=tx+16c -> 16 lanes hit 16 distinct banks.

__global__ __launch_bounds__(256) void softhd_main(
    const float* __restrict__ v1, const int* __restrict__ sz1,
    const float* __restrict__ v2, const int* __restrict__ sz2,
    float* __restrict__ out)
{
    __shared__ float s1[N1C * PITCH];
    __shared__ float s2[N2C * PITCH];
    __shared__ float sx2[N1C];
    __shared__ float sy2[N2C];
    __shared__ unsigned sbm1[N2C];  // per-j min over valid i (float bits)
    __shared__ unsigned sbm2[N1C];  // per-i min over valid j
    __shared__ float swsum[4];

    const int tid = threadIdx.x;
    const int b1 = blockIdx.x >> 6;
    const int b2 = blockIdx.x & 63;
    const int tx = tid & 15;
    const int ty = tid >> 4;
    const int i0 = ty * 8;

    const float* g1 = v1 + (size_t)b1 * N1C * DC;
    const float* g2 = v2 + (size_t)b2 * N2C * DC;

    float acc[8][8];
#pragma unroll
    for (int r = 0; r < 8; ++r)
#pragma unroll
        for (int c = 0; c < 8; ++c) acc[r][c] = 0.f;

    float x2p = 0.f, y2p = 0.f;

    if (tid < 128) sbm1[tid] = 0x7F800000u;   // +inf bits
    else           sbm2[tid - 128] = 0x7F800000u;

    for (int ck = 0; ck < DC / KT; ++ck) {
        __syncthreads();  // protect LDS reuse from previous chunk
#pragma unroll
        for (int it = 0; it < 4; ++it) {
            int f = tid + it * 256;          // 0..1023
            int row = f >> 3;
            int c4 = (f & 7) * 4;
            float4 q1 = *(const float4*)(g1 + row * DC + ck * KT + c4);
            float4 q2 = *(const float4*)(g2 + row * DC + ck * KT + c4);
            *(float4*)(s1 + row * PITCH + c4) = q1;
            *(float4*)(s2 + row * PITCH + c4) = q2;
        }
        __syncthreads();
        // per-row squared-norm partials (thread t owns one row)
        {
            const float* srow = (tid < 128) ? (s1 + tid * PITCH)
                                            : (s2 + (tid - 128) * PITCH);
            float p = 0.f;
#pragma unroll
            for (int k = 0; k < KT; k += 4) {
                float4 q = *(const float4*)(srow + k);
                p += q.x*q.x + q.y*q.y + q.z*q.z + q.w*q.w;
            }
            if (tid < 128) x2p += p; else y2p += p;
        }
        // main register-tiled dot-product accumulation
#pragma unroll
        for (int kt = 0; kt < KT; kt += 4) {
            float4 a[8], b[8];
#pragma unroll
            for (int r = 0; r < 8; ++r)
                a[r] = *(const float4*)(s1 + (i0 + r) * PITCH + kt);
#pragma unroll
            for (int c = 0; c < 8; ++c)
                b[c] = *(const float4*)(s2 + (tx + 16 * c) * PITCH + kt);
#pragma unroll
            for (int r = 0; r < 8; ++r)
#pragma unroll
                for (int c = 0; c < 8; ++c)
                    acc[r][c] += a[r].x*b[c].x + a[r].y*b[c].y
                               + a[r].z*b[c].z + a[r].w*b[c].w;
        }
    }
    if (tid < 128) sx2[tid] = x2p; else sy2[tid - 128] = y2p;
    __syncthreads();

    const int n1 = min(max(sz1[b1], 0), N1C);
    const int n2 = min(max(sz2[b2], 0), N2C);

    const float INF = __builtin_inff();
    float minj[8], mini[8];
#pragma unroll
    for (int c = 0; c < 8; ++c) minj[c] = INF;
#pragma unroll
    for (int r = 0; r < 8; ++r) mini[r] = INF;

#pragma unroll
    for (int r = 0; r < 8; ++r) {
        int i = i0 + r;
#pragma unroll
        for (int c = 0; c < 8; ++c) {
            int j = tx + 16 * c;
            float sq = sx2[i] + sy2[j] - 2.f * acc[r][c];
            float dd = sqrtf(fmaxf(sq, 0.f));
            if (i < n1) minj[c] = fminf(minj[c], dd);
            if (j < n2) mini[r] = fminf(mini[r], dd);
        }
    }
#pragma unroll
    for (int c = 0; c < 8; ++c)
        atomicMin(&sbm1[tx + 16 * c], __float_as_uint(minj[c]));
#pragma unroll
    for (int r = 0; r < 8; ++r)
        atomicMin(&sbm2[i0 + r], __float_as_uint(mini[r]));
    __syncthreads();

    float v = 0.f;
    if (tid < 128) {
        if (n1 > 0 && tid < n2) v += __uint_as_float(sbm1[tid]);
        if (n2 > 0 && tid < n1) v += __uint_as_float(sbm2[tid]);
    }
#pragma unroll
    for (int off = 32; off >= 1; off >>= 1) v += __shfl_down(v, off);
    if ((tid & 63) == 0) swsum[tid >> 6] = v;
    __syncthreads();
    if (tid == 0) out[blockIdx.x] = swsum[0] + swsum[1] + swsum[2] + swsum[3];
}

extern "C" void kernel_launch(void* const* d_in, const int* in_sizes, int n_in,
                              void* d_out, int out_size, void* d_ws, size_t ws_size,
                              hipStream_t stream) {
    const float* v1  = (const float*)d_in[0];
    const int*   sz1 = (const int*)d_in[1];
    const float* v2  = (const float*)d_in[2];
    const int*   sz2 = (const int*)d_in[3];
    float* out = (float*)d_out;
    (void)in_sizes; (void)n_in; (void)out_size; (void)d_ws; (void)ws_size;

    softhd_main<<<dim3(64 * 64), dim3(256), 0, stream>>>(v1, sz1, v2, sz2, out);
}

// Round 2
// 86.705 us; speedup vs baseline: 32.5707x; 32.5707x over previous
//
#include <hip/hip_runtime.h>
#include <math.h>

// SoftHd via bf16 MFMA.
// v1: (64,128,128) f32, sz1: (64,), v2: (64,128,128) f32, sz2: (64,), out (64,64) f32.
// out[b1,b2] = sum_{j<sz2} min_{i<sz1} dist[i,j] + sum_{i<sz1} min_{j<sz2} dist[i,j]
// (reference's global-max fill never survives the masked mins / explicit zeroing).
// dist via gemm identity; xy GEMM on bf16-rounded inputs (MFMA 16x16x32_bf16),
// norms computed in fp32 FROM THE ROUNDED VALUES for consistency.

typedef __attribute__((ext_vector_type(8))) short short8;
typedef __attribute__((ext_vector_type(4))) float f32x4;
typedef unsigned int u32;
typedef unsigned short ushort_t;

static __device__ __forceinline__ ushort_t f32_to_bf16_rne(float f) {
    u32 b = __float_as_uint(f);
    b += 0x7FFFu + ((b >> 16) & 1u);
    return (ushort_t)(b >> 16);
}

// ---------------------------------------------------------------------------
// Pre-kernel: convert both tensors to bf16 with a per-row XOR chunk swizzle
// (16B chunk p = c ^ (r&7)) so a LINEAR global_load_lds copy produces a
// bank-conflict-free LDS layout for MFMA fragment reads. Also emits per-row
// squared norms (fp32, of the rounded values).
// grid: 262144 threads = 2 tensors * 64 b * 128 rows * 16 chunks.
// ---------------------------------------------------------------------------
__global__ __launch_bounds__(256) void softhd_pre(
    const float* __restrict__ v1, const float* __restrict__ v2,
    ushort_t* __restrict__ v1b, ushort_t* __restrict__ v2b,
    float* __restrict__ x2g, float* __restrict__ y2g)
{
    int flat = blockIdx.x * 256 + threadIdx.x;
    int c = flat & 15;
    int r = (flat >> 4) & 127;
    int b = (flat >> 11) & 63;
    int t = flat >> 17;

    const float* src = (t ? v2 : v1) + ((size_t)((b << 7) + r) << 7) + c * 8;
    ushort_t* dst = (t ? v2b : v1b) + ((size_t)((b << 7) + r) << 7);

    float4 q0 = *(const float4*)(src);
    float4 q1 = *(const float4*)(src + 4);

    ushort_t h[8];
    h[0] = f32_to_bf16_rne(q0.x); h[1] = f32_to_bf16_rne(q0.y);
    h[2] = f32_to_bf16_rne(q0.z); h[3] = f32_to_bf16_rne(q0.w);
    h[4] = f32_to_bf16_rne(q1.x); h[5] = f32_to_bf16_rne(q1.y);
    h[6] = f32_to_bf16_rne(q1.z); h[7] = f32_to_bf16_rne(q1.w);

    float p = 0.f;
#pragma unroll
    for (int k = 0; k < 8; ++k) {
        float fv = __uint_as_float((u32)h[k] << 16);
        p += fv * fv;
    }

    uint4 w;
    w.x = (u32)h[0] | ((u32)h[1] << 16);
    w.y = (u32)h[2] | ((u32)h[3] << 16);
    w.z = (u32)h[4] | ((u32)h[5] << 16);
    w.w = (u32)h[6] | ((u32)h[7] << 16);
    *(uint4*)(dst + ((c ^ (r & 7)) << 3)) = w;

    // reduce the 16 chunk-partials of this row (lanes share high bits)
    p += __shfl_xor(p, 1);
    p += __shfl_xor(p, 2);
    p += __shfl_xor(p, 4);
    p += __shfl_xor(p, 8);
    if (c == 0) (t ? y2g : x2g)[(b << 7) + r] = p;
}

// ---------------------------------------------------------------------------
// Main kernel: one block per (b1,b2). 4 waves, 2x2 quadrant split (64x64 out
// per wave). Full 128x128 bf16 panels staged once via global_load_lds w=16.
// ---------------------------------------------------------------------------
__global__ __launch_bounds__(256) void softhd_mfma(
    const ushort_t* __restrict__ v1b, const ushort_t* __restrict__ v2b,
    const float* __restrict__ x2g, const float* __restrict__ y2g,
    const int* __restrict__ sz1, const int* __restrict__ sz2,
    float* __restrict__ out)
{
    __shared__ __align__(16) ushort_t s1[128 * 128];
    __shared__ __align__(16) ushort_t s2[128 * 128];
    __shared__ float sx2[128], sy2[128];
    __shared__ u32 sbm1[128], sbm2[128];
    __shared__ float swsum[4];

    const int tid = threadIdx.x;
    const int lane = tid & 63;
    const int wid = tid >> 6;
    // XCD-bijective swizzle (4096 % 8 == 0): each XCD gets a contiguous chunk.
    const int bid = ((blockIdx.x & 7) << 9) | (blockIdx.x >> 3);
    const int b1 = bid >> 6, b2 = bid & 63;

    // ---- stage both bf16 panels (32 KB each): 8 x 16B per thread per panel
    {
        const char* g1 = (const char*)(v1b + ((size_t)b1 << 14));
        const char* g2 = (const char*)(v2b + ((size_t)b2 << 14));
#pragma unroll
        for (int it = 0; it < 8; ++it) {
            int boff = it * 4096 + wid * 1024 + lane * 16;
            __builtin_amdgcn_global_load_lds(
                (const __attribute__((address_space(1))) u32*)(g1 + boff),
                (__attribute__((address_space(3))) u32*)((char*)s1 + boff),
                16, 0, 0);
            __builtin_amdgcn_global_load_lds(
                (const __attribute__((address_space(1))) u32*)(g2 + boff),
                (__attribute__((address_space(3))) u32*)((char*)s2 + boff),
                16, 0, 0);
        }
    }
    if (tid < 128) {
        sx2[tid] = x2g[(b1 << 7) + tid];
        sbm1[tid] = 0x7F800000u;            // +inf bits
    } else {
        sy2[tid - 128] = y2g[(b2 << 7) + (tid - 128)];
        sbm2[tid - 128] = 0x7F800000u;
    }
    __syncthreads();   // compiler drains vmcnt before the barrier

    const int qr = wid >> 1, qc = wid & 1;
    const int ibase = qr << 6, jbase = qc << 6;
    const int rf = lane & 15, kg = lane >> 4;
    const int h = rf & 7;                   // row&7 is f-independent (16 | fstride)

    const ushort_t* a_base = s1 + ((ibase + rf) << 7);
    const ushort_t* b_base = s2 + ((jbase + rf) << 7);

    f32x4 acc[4][4];
#pragma unroll
    for (int fi = 0; fi < 4; ++fi)
#pragma unroll
        for (int fj = 0; fj < 4; ++fj)
            acc[fi][fj] = (f32x4){0.f, 0.f, 0.f, 0.f};

#pragma unroll
    for (int s = 0; s < 4; ++s) {
        const int p8 = ((s * 4 + kg) ^ h) << 3;   // physical chunk * 8 elems
        short8 a[4], b[4];
#pragma unroll
        for (int f = 0; f < 4; ++f) {
            a[f] = *(const short8*)(a_base + f * 2048 + p8);
            b[f] = *(const short8*)(b_base + f * 2048 + p8);
        }
#pragma unroll
        for (int fi = 0; fi < 4; ++fi)
#pragma unroll
            for (int fj = 0; fj < 4; ++fj)
                acc[fi][fj] = __builtin_amdgcn_mfma_f32_16x16x32_bf16(
                    a[fi], b[fj], acc[fi][fj], 0, 0, 0);
    }

    const int n1 = min(max(sz1[b1], 0), 128);
    const int n2 = min(max(sz2[b2], 0), 128);
    const float INF = __builtin_inff();

    float minj[4], mini[16];
#pragma unroll
    for (int f = 0; f < 4; ++f) minj[f] = INF;
#pragma unroll
    for (int t = 0; t < 16; ++t) mini[t] = INF;

#pragma unroll
    for (int fi = 0; fi < 4; ++fi) {
#pragma unroll
        for (int q = 0; q < 4; ++q) {
            const int i = ibase + fi * 16 + kg * 4 + q;
            const float xi = sx2[i];
            const bool iv = i < n1;
#pragma unroll
            for (int fj = 0; fj < 4; ++fj) {
                const int j = jbase + fj * 16 + rf;
                float sq = xi + sy2[j] - 2.f * acc[fi][fj][q];
                float d = sqrtf(fmaxf(sq, 0.f));
                if (iv) minj[fj] = fminf(minj[fj], d);
                if (j < n2) mini[fi * 4 + q] = fminf(mini[fi * 4 + q], d);
            }
        }
    }

    // min over i lives across the 4 row-groups (lane bits 4..5) of both qr waves
#pragma unroll
    for (int fj = 0; fj < 4; ++fj) {
        float m = minj[fj];
        m = fminf(m, __shfl_xor(m, 16));
        m = fminf(m, __shfl_xor(m, 32));
        if (kg == 0) atomicMin(&sbm1[jbase + fj * 16 + rf], __float_as_uint(m));
    }
    // min over j lives across the 16 col lanes (lane bits 0..3) of both qc waves
#pragma unroll
    for (int t = 0; t < 16; ++t) {
        float m = mini[t];
        m = fminf(m, __shfl_xor(m, 1));
        m = fminf(m, __shfl_xor(m, 2));
        m = fminf(m, __shfl_xor(m, 4));
        m = fminf(m, __shfl_xor(m, 8));
        if (rf == 0)
            atomicMin(&sbm2[ibase + (t >> 2) * 16 + kg * 4 + (t & 3)],
                      __float_as_uint(m));
    }
    __syncthreads();

    float v = 0.f;
    if (tid < 128) {
        if (n1 > 0 && tid < n2) v += __uint_as_float(sbm1[tid]);
        if (n2 > 0 && tid < n1) v += __uint_as_float(sbm2[tid]);
    }
#pragma unroll
    for (int off = 32; off >= 1; off >>= 1) v += __shfl_down(v, off);
    if (lane == 0) swsum[wid] = v;
    __syncthreads();
    if (tid == 0) out[bid] = swsum[0] + swsum[1] + swsum[2] + swsum[3];
}

extern "C" void kernel_launch(void* const* d_in, const int* in_sizes, int n_in,
                              void* d_out, int out_size, void* d_ws, size_t ws_size,
                              hipStream_t stream) {
    const float* v1  = (const float*)d_in[0];
    const int*   sz1 = (const int*)d_in[1];
    const float* v2  = (const float*)d_in[2];
    const int*   sz2 = (const int*)d_in[3];
    float* out = (float*)d_out;
    (void)in_sizes; (void)n_in; (void)out_size; (void)ws_size;

    char* ws = (char*)d_ws;
    ushort_t* v1b = (ushort_t*)ws;                       // 2 MB
    ushort_t* v2b = (ushort_t*)(ws + (2u << 20));        // 2 MB
    float*    x2g = (float*)(ws + (4u << 20));           // 32 KB
    float*    y2g = x2g + 64 * 128;                      // 32 KB

    softhd_pre<<<dim3(1024), dim3(256), 0, stream>>>(v1, v2, v1b, v2b, x2g, y2g);
    softhd_mfma<<<dim3(4096), dim3(256), 0, stream>>>(v1b, v2b, x2g, y2g,
                                                      sz1, sz2, out);
}

// Round 3
// 73.188 us; speedup vs baseline: 38.5865x; 1.1847x over previous
//
#include <hip/hip_runtime.h>
#include <math.h>

// SoftHd via bf16 MFMA.
// v1: (64,128,128) f32, sz1: (64,), v2: (64,128,128) f32, sz2: (64,), out (64,64) f32.
// out[b1,b2] = sum_{j<sz2} min_{i<sz1} dist[i,j] + sum_{i<sz1} min_{j<sz2} dist[i,j]
// (reference's global-max fill never survives the masked mins / explicit zeroing).
// dist via gemm identity on bf16-rounded inputs (MFMA 16x16x32_bf16).
// KEY: sqrt is monotone -> compute mins on (norm - 2xy) partials, apply
// +other-norm / clamp / sqrt only AFTER the min reductions (256 sqrts/block,
// not 16384). Masking folds into +INF operands.

typedef __attribute__((ext_vector_type(8))) short short8;
typedef __attribute__((ext_vector_type(4))) float f32x4;
typedef unsigned int u32;
typedef unsigned short ushort_t;

static __device__ __forceinline__ ushort_t f32_to_bf16_rne(float f) {
    u32 b = __float_as_uint(f);
    b += 0x7FFFu + ((b >> 16) & 1u);
    return (ushort_t)(b >> 16);
}

// ---------------------------------------------------------------------------
// Pre-kernel: f32 -> bf16 with per-row XOR chunk swizzle (16B chunk p = c ^
// (r&7)) so a LINEAR global_load_lds copy yields a conflict-free LDS layout.
// Also emits per-row squared norms (fp32, of the ROUNDED values).
// ---------------------------------------------------------------------------
__global__ __launch_bounds__(256) void softhd_pre(
    const float* __restrict__ v1, const float* __restrict__ v2,
    ushort_t* __restrict__ v1b, ushort_t* __restrict__ v2b,
    float* __restrict__ x2g, float* __restrict__ y2g)
{
    int flat = blockIdx.x * 256 + threadIdx.x;
    int c = flat & 15;
    int r = (flat >> 4) & 127;
    int b = (flat >> 11) & 63;
    int t = flat >> 17;

    const float* src = (t ? v2 : v1) + ((size_t)((b << 7) + r) << 7) + c * 8;
    ushort_t* dst = (t ? v2b : v1b) + ((size_t)((b << 7) + r) << 7);

    float4 q0 = *(const float4*)(src);
    float4 q1 = *(const float4*)(src + 4);

    ushort_t h[8];
    h[0] = f32_to_bf16_rne(q0.x); h[1] = f32_to_bf16_rne(q0.y);
    h[2] = f32_to_bf16_rne(q0.z); h[3] = f32_to_bf16_rne(q0.w);
    h[4] = f32_to_bf16_rne(q1.x); h[5] = f32_to_bf16_rne(q1.y);
    h[6] = f32_to_bf16_rne(q1.z); h[7] = f32_to_bf16_rne(q1.w);

    float p = 0.f;
#pragma unroll
    for (int k = 0; k < 8; ++k) {
        float fv = __uint_as_float((u32)h[k] << 16);
        p += fv * fv;
    }

    uint4 w;
    w.x = (u32)h[0] | ((u32)h[1] << 16);
    w.y = (u32)h[2] | ((u32)h[3] << 16);
    w.z = (u32)h[4] | ((u32)h[5] << 16);
    w.w = (u32)h[6] | ((u32)h[7] << 16);
    *(uint4*)(dst + ((c ^ (r & 7)) << 3)) = w;

    p += __shfl_xor(p, 1);
    p += __shfl_xor(p, 2);
    p += __shfl_xor(p, 4);
    p += __shfl_xor(p, 8);
    if (c == 0) (t ? y2g : x2g)[(b << 7) + r] = p;
}

// ---------------------------------------------------------------------------
// Main kernel: one block per (b1,b2). 4 waves, 2x2 quadrant split (64x64 out
// per wave). Full 128x128 bf16 panels staged once via global_load_lds w=16.
// ---------------------------------------------------------------------------
__global__ __launch_bounds__(256) void softhd_mfma(
    const ushort_t* __restrict__ v1b, const ushort_t* __restrict__ v2b,
    const float* __restrict__ x2g, const float* __restrict__ y2g,
    const int* __restrict__ sz1, const int* __restrict__ sz2,
    float* __restrict__ out)
{
    __shared__ __align__(16) ushort_t s1[128 * 128];
    __shared__ __align__(16) ushort_t s2[128 * 128];
    __shared__ float sx2[128], sy2[128];
    __shared__ u32 sbm1[128], sbm2[128];
    __shared__ float swsum[4];

    const int tid = threadIdx.x;
    const int lane = tid & 63;
    const int wid = tid >> 6;
    // XCD-bijective swizzle (4096 % 8 == 0).
    const int bid = ((blockIdx.x & 7) << 9) | (blockIdx.x >> 3);
    const int b1 = bid >> 6, b2 = bid & 63;

    {
        const char* g1 = (const char*)(v1b + ((size_t)b1 << 14));
        const char* g2 = (const char*)(v2b + ((size_t)b2 << 14));
#pragma unroll
        for (int it = 0; it < 8; ++it) {
            int boff = it * 4096 + wid * 1024 + lane * 16;
            __builtin_amdgcn_global_load_lds(
                (const __attribute__((address_space(1))) u32*)(g1 + boff),
                (__attribute__((address_space(3))) u32*)((char*)s1 + boff),
                16, 0, 0);
            __builtin_amdgcn_global_load_lds(
                (const __attribute__((address_space(1))) u32*)(g2 + boff),
                (__attribute__((address_space(3))) u32*)((char*)s2 + boff),
                16, 0, 0);
        }
    }
    if (tid < 128) {
        sx2[tid] = x2g[(b1 << 7) + tid];
        sbm1[tid] = 0x7F800000u;            // +inf bits
    } else {
        sy2[tid - 128] = y2g[(b2 << 7) + (tid - 128)];
        sbm2[tid - 128] = 0x7F800000u;
    }
    __syncthreads();

    const int qr = wid >> 1, qc = wid & 1;
    const int ibase = qr << 6, jbase = qc << 6;
    const int rf = lane & 15, kg = lane >> 4;
    const int h = rf & 7;

    const ushort_t* a_base = s1 + ((ibase + rf) << 7);
    const ushort_t* b_base = s2 + ((jbase + rf) << 7);

    f32x4 acc[4][4];
#pragma unroll
    for (int fi = 0; fi < 4; ++fi)
#pragma unroll
        for (int fj = 0; fj < 4; ++fj)
            acc[fi][fj] = (f32x4){0.f, 0.f, 0.f, 0.f};

#pragma unroll
    for (int s = 0; s < 4; ++s) {
        const int p8 = ((s * 4 + kg) ^ h) << 3;
        short8 a[4], b[4];
#pragma unroll
        for (int f = 0; f < 4; ++f) {
            a[f] = *(const short8*)(a_base + f * 2048 + p8);
            b[f] = *(const short8*)(b_base + f * 2048 + p8);
        }
#pragma unroll
        for (int fi = 0; fi < 4; ++fi)
#pragma unroll
            for (int fj = 0; fj < 4; ++fj)
                acc[fi][fj] = __builtin_amdgcn_mfma_f32_16x16x32_bf16(
                    a[fi], b[fj], acc[fi][fj], 0, 0, 0);
    }

    const int n1 = min(max(sz1[b1], 0), 128);
    const int n2 = min(max(sz2[b2], 0), 128);
    const float INF = __builtin_inff();

    // Masking folded into operands: invalid rows/cols contribute +INF.
    float xieff[16], yjeff[4];
#pragma unroll
    for (int fi = 0; fi < 4; ++fi)
#pragma unroll
        for (int q = 0; q < 4; ++q) {
            int i = ibase + fi * 16 + kg * 4 + q;
            xieff[fi * 4 + q] = (i < n1) ? sx2[i] : INF;
        }
#pragma unroll
    for (int fj = 0; fj < 4; ++fj) {
        int j = jbase + fj * 16 + rf;
        yjeff[fj] = (j < n2) ? sy2[j] : INF;
    }

    float minj[4], mini[16];
#pragma unroll
    for (int fj = 0; fj < 4; ++fj) minj[fj] = INF;
#pragma unroll
    for (int t = 0; t < 16; ++t) mini[t] = INF;

    // 4 VALU per element: 2 fma (inline -2.0) + 2 min. No sqrt here.
#pragma unroll
    for (int fi = 0; fi < 4; ++fi)
#pragma unroll
        for (int fj = 0; fj < 4; ++fj)
#pragma unroll
            for (int q = 0; q < 4; ++q) {
                float t = acc[fi][fj][q];
                minj[fj] = fminf(minj[fj], fmaf(t, -2.f, xieff[fi * 4 + q]));
                mini[fi * 4 + q] =
                    fminf(mini[fi * 4 + q], fmaf(t, -2.f, yjeff[fj]));
            }

    // Column mins: reduce over this wave's 64 rows (lane bits 4..5), then
    // finalize (add y2, clamp, sqrt) and combine across qr waves via atomicMin
    // (safe: non-negative after clamp; sqrt/min commute by monotonicity).
#pragma unroll
    for (int fj = 0; fj < 4; ++fj) {
        float m = minj[fj];
        m = fminf(m, __shfl_xor(m, 16));
        m = fminf(m, __shfl_xor(m, 32));
        if (kg == 0) {
            int j = jbase + fj * 16 + rf;
            float d = sqrtf(fmaxf(m + sy2[j], 0.f));
            atomicMin(&sbm1[j], __float_as_uint(d));
        }
    }
    // Row mins: reduce over this wave's 64 cols (lane bits 0..3).
#pragma unroll
    for (int t = 0; t < 16; ++t) {
        float m = mini[t];
        m = fminf(m, __shfl_xor(m, 1));
        m = fminf(m, __shfl_xor(m, 2));
        m = fminf(m, __shfl_xor(m, 4));
        m = fminf(m, __shfl_xor(m, 8));
        if (rf == 0) {
            int i = ibase + (t >> 2) * 16 + kg * 4 + (t & 3);
            float d = sqrtf(fmaxf(m + sx2[i], 0.f));
            atomicMin(&sbm2[i], __float_as_uint(d));
        }
    }
    __syncthreads();

    float v = 0.f;
    if (tid < 128) {
        if (n1 > 0 && tid < n2) v += __uint_as_float(sbm1[tid]);
        if (n2 > 0 && tid < n1) v += __uint_as_float(sbm2[tid]);
    }
#pragma unroll
    for (int off = 32; off >= 1; off >>= 1) v += __shfl_down(v, off);
    if (lane == 0) swsum[wid] = v;
    __syncthreads();
    if (tid == 0) out[bid] = swsum[0] + swsum[1] + swsum[2] + swsum[3];
}

extern "C" void kernel_launch(void* const* d_in, const int* in_sizes, int n_in,
                              void* d_out, int out_size, void* d_ws, size_t ws_size,
                              hipStream_t stream) {
    const float* v1  = (const float*)d_in[0];
    const int*   sz1 = (const int*)d_in[1];
    const float* v2  = (const float*)d_in[2];
    const int*   sz2 = (const int*)d_in[3];
    float* out = (float*)d_out;
    (void)in_sizes; (void)n_in; (void)out_size; (void)ws_size;

    char* ws = (char*)d_ws;
    ushort_t* v1b = (ushort_t*)ws;                       // 2 MB
    ushort_t* v2b = (ushort_t*)(ws + (2u << 20));        // 2 MB
    float*    x2g = (float*)(ws + (4u << 20));           // 32 KB
    float*    y2g = x2g + 64 * 128;                      // 32 KB

    softhd_pre<<<dim3(1024), dim3(256), 0, stream>>>(v1, v2, v1b, v2b, x2g, y2g);
    softhd_mfma<<<dim3(4096), dim3(256), 0, stream>>>(v1b, v2b, x2g, y2g,
                                                      sz1, sz2, out);
}

// Round 4
// 49.821 us; speedup vs baseline: 56.6835x; 1.4690x over previous
//
#include <hip/hip_runtime.h>
#include <math.h>

// SoftHd via bf16 MFMA, K-split for occupancy.
// v1: (64,128,128) f32, sz1: (64,), v2: (64,128,128) f32, sz2: (64,), out (64,64) f32.
// out[b1,b2] = sum_{j<sz2} min_{i<sz1} dist[i,j] + sum_{i<sz1} min_{j<sz2} dist[i,j]
// dist via gemm identity on bf16-rounded inputs (MFMA 16x16x32_bf16).
// sqrt is monotone -> mins computed on (norm - 2xy), sqrt after reduction.
// K=128 split into 2 halves of 64, single-buffered LDS (34.9 KB) -> 4 blocks/CU.

typedef __attribute__((ext_vector_type(8))) short short8;
typedef __attribute__((ext_vector_type(4))) float f32x4;
typedef unsigned int u32;
typedef unsigned short ushort_t;

static __device__ __forceinline__ ushort_t f32_to_bf16_rne(float f) {
    u32 b = __float_as_uint(f);
    b += 0x7FFFu + ((b >> 16) & 1u);
    return (ushort_t)(b >> 16);
}

// ---------------------------------------------------------------------------
// Pre-kernel: f32 -> bf16 with per-row XOR chunk swizzle (16B chunk p = c ^
// (r&7)); the XOR stays within each 8-chunk half, so K-halves remain
// contiguous 128B runs per row. Also emits per-row squared norms (fp32 of the
// ROUNDED values).
// ---------------------------------------------------------------------------
__global__ __launch_bounds__(256) void softhd_pre(
    const float* __restrict__ v1, const float* __restrict__ v2,
    ushort_t* __restrict__ v1b, ushort_t* __restrict__ v2b,
    float* __restrict__ x2g, float* __restrict__ y2g)
{
    int flat = blockIdx.x * 256 + threadIdx.x;
    int c = flat & 15;
    int r = (flat >> 4) & 127;
    int b = (flat >> 11) & 63;
    int t = flat >> 17;

    const float* src = (t ? v2 : v1) + ((size_t)((b << 7) + r) << 7) + c * 8;
    ushort_t* dst = (t ? v2b : v1b) + ((size_t)((b << 7) + r) << 7);

    float4 q0 = *(const float4*)(src);
    float4 q1 = *(const float4*)(src + 4);

    ushort_t h[8];
    h[0] = f32_to_bf16_rne(q0.x); h[1] = f32_to_bf16_rne(q0.y);
    h[2] = f32_to_bf16_rne(q0.z); h[3] = f32_to_bf16_rne(q0.w);
    h[4] = f32_to_bf16_rne(q1.x); h[5] = f32_to_bf16_rne(q1.y);
    h[6] = f32_to_bf16_rne(q1.z); h[7] = f32_to_bf16_rne(q1.w);

    float p = 0.f;
#pragma unroll
    for (int k = 0; k < 8; ++k) {
        float fv = __uint_as_float((u32)h[k] << 16);
        p += fv * fv;
    }

    uint4 w;
    w.x = (u32)h[0] | ((u32)h[1] << 16);
    w.y = (u32)h[2] | ((u32)h[3] << 16);
    w.z = (u32)h[4] | ((u32)h[5] << 16);
    w.w = (u32)h[6] | ((u32)h[7] << 16);
    *(uint4*)(dst + ((c ^ (r & 7)) << 3)) = w;

    p += __shfl_xor(p, 1);
    p += __shfl_xor(p, 2);
    p += __shfl_xor(p, 4);
    p += __shfl_xor(p, 8);
    if (c == 0) (t ? y2g : x2g)[(b << 7) + r] = p;
}

// Stage one 64-col K-half of both panels: 16KB each, 4 x 2 x 16B per thread.
// Row r occupies bytes [srcoff, srcoff+128) of its 256B global row; LDS dest
// is linear (m*16), satisfying global_load_lds' uniform-base + lane*16 rule.
static __device__ __forceinline__ void stage_half(
    const char* g1, const char* g2, ushort_t* s1, ushort_t* s2,
    int tid, int srcoff)
{
#pragma unroll
    for (int it = 0; it < 4; ++it) {
        int m = it * 256 + tid;                       // 16B-chunk idx, 0..1023
        int so = ((m >> 3) << 8) + srcoff + ((m & 7) << 4);
        int dof = m << 4;
        __builtin_amdgcn_global_load_lds(
            (const __attribute__((address_space(1))) u32*)(g1 + so),
            (__attribute__((address_space(3))) u32*)((char*)s1 + dof),
            16, 0, 0);
        __builtin_amdgcn_global_load_lds(
            (const __attribute__((address_space(1))) u32*)(g2 + so),
            (__attribute__((address_space(3))) u32*)((char*)s2 + dof),
            16, 0, 0);
    }
}

// ---------------------------------------------------------------------------
// Main kernel: one block per (b1,b2). 4 waves, 2x2 quadrant split (64x64 out
// per wave). K processed in 2 single-buffered halves -> 34.9 KB LDS.
// ---------------------------------------------------------------------------
__global__ __launch_bounds__(256, 4) void softhd_mfma(
    const ushort_t* __restrict__ v1b, const ushort_t* __restrict__ v2b,
    const float* __restrict__ x2g, const float* __restrict__ y2g,
    const int* __restrict__ sz1, const int* __restrict__ sz2,
    float* __restrict__ out)
{
    __shared__ __align__(16) ushort_t s1[128 * 64];
    __shared__ __align__(16) ushort_t s2[128 * 64];
    __shared__ float sx2[128], sy2[128];
    __shared__ u32 sbm1[128], sbm2[128];
    __shared__ float swsum[4];

    const int tid = threadIdx.x;
    const int lane = tid & 63;
    const int wid = tid >> 6;
    // XCD-bijective swizzle (4096 % 8 == 0).
    const int bid = ((blockIdx.x & 7) << 9) | (blockIdx.x >> 3);
    const int b1 = bid >> 6, b2 = bid & 63;

    const char* g1 = (const char*)(v1b + ((size_t)b1 << 14));
    const char* g2 = (const char*)(v2b + ((size_t)b2 << 14));

    stage_half(g1, g2, s1, s2, tid, 0);

    if (tid < 128) {
        sx2[tid] = x2g[(b1 << 7) + tid];
        sbm1[tid] = 0x7F800000u;            // +inf bits
    } else {
        sy2[tid - 128] = y2g[(b2 << 7) + (tid - 128)];
        sbm2[tid - 128] = 0x7F800000u;
    }
    __syncthreads();

    const int qr = wid >> 1, qc = wid & 1;
    const int ibase = qr << 6, jbase = qc << 6;
    const int rf = lane & 15, kg = lane >> 4;
    const int h = rf & 7;

    const ushort_t* a_base = s1 + ((ibase + rf) << 6);   // row stride 64 elems
    const ushort_t* b_base = s2 + ((jbase + rf) << 6);

    f32x4 acc[4][4];
#pragma unroll
    for (int fi = 0; fi < 4; ++fi)
#pragma unroll
        for (int fj = 0; fj < 4; ++fj)
            acc[fi][fj] = (f32x4){0.f, 0.f, 0.f, 0.f};

#pragma unroll
    for (int half = 0; half < 2; ++half) {
        if (half == 1) {
            __syncthreads();                 // everyone done reading half 0
            stage_half(g1, g2, s1, s2, tid, 128);
            __syncthreads();                 // half 1 resident (vmcnt drained)
        }
#pragma unroll
        for (int s = 0; s < 2; ++s) {
            const int p8 = (((s << 2) + kg) ^ h) << 3;  // phys chunk * 8 elems
            short8 a[4], b[4];
#pragma unroll
            for (int f = 0; f < 4; ++f) {
                a[f] = *(const short8*)(a_base + (f << 10) + p8);
                b[f] = *(const short8*)(b_base + (f << 10) + p8);
            }
#pragma unroll
            for (int fi = 0; fi < 4; ++fi)
#pragma unroll
                for (int fj = 0; fj < 4; ++fj)
                    acc[fi][fj] = __builtin_amdgcn_mfma_f32_16x16x32_bf16(
                        a[fi], b[fj], acc[fi][fj], 0, 0, 0);
        }
    }

    const int n1 = min(max(sz1[b1], 0), 128);
    const int n2 = min(max(sz2[b2], 0), 128);
    const float INF = __builtin_inff();

    float xieff[16], yjeff[4];
#pragma unroll
    for (int fi = 0; fi < 4; ++fi)
#pragma unroll
        for (int q = 0; q < 4; ++q) {
            int i = ibase + fi * 16 + kg * 4 + q;
            xieff[fi * 4 + q] = (i < n1) ? sx2[i] : INF;
        }
#pragma unroll
    for (int fj = 0; fj < 4; ++fj) {
        int j = jbase + fj * 16 + rf;
        yjeff[fj] = (j < n2) ? sy2[j] : INF;
    }

    float minj[4], mini[16];
#pragma unroll
    for (int fj = 0; fj < 4; ++fj) minj[fj] = INF;
#pragma unroll
    for (int t = 0; t < 16; ++t) mini[t] = INF;

    // 4 VALU per element: 2 fma (inline -2.0) + 2 min. No sqrt here.
#pragma unroll
    for (int fi = 0; fi < 4; ++fi)
#pragma unroll
        for (int fj = 0; fj < 4; ++fj)
#pragma unroll
            for (int q = 0; q < 4; ++q) {
                float t = acc[fi][fj][q];
                minj[fj] = fminf(minj[fj], fmaf(t, -2.f, xieff[fi * 4 + q]));
                mini[fi * 4 + q] =
                    fminf(mini[fi * 4 + q], fmaf(t, -2.f, yjeff[fj]));
            }

    // Column mins: reduce over this wave's 64 rows (lane bits 4..5), finalize
    // (add y2, clamp, sqrt — monotone, commutes with min), combine via LDS
    // atomicMin on bits (non-negative floats).
#pragma unroll
    for (int fj = 0; fj < 4; ++fj) {
        float m = minj[fj];
        m = fminf(m, __shfl_xor(m, 16));
        m = fminf(m, __shfl_xor(m, 32));
        if (kg == 0) {
            int j = jbase + fj * 16 + rf;
            float d = sqrtf(fmaxf(m + sy2[j], 0.f));
            atomicMin(&sbm1[j], __float_as_uint(d));
        }
    }
    // Row mins: reduce over this wave's 64 cols (lane bits 0..3).
#pragma unroll
    for (int t = 0; t < 16; ++t) {
        float m = mini[t];
        m = fminf(m, __shfl_xor(m, 1));
        m = fminf(m, __shfl_xor(m, 2));
        m = fminf(m, __shfl_xor(m, 4));
        m = fminf(m, __shfl_xor(m, 8));
        if (rf == 0) {
            int i = ibase + (t >> 2) * 16 + kg * 4 + (t & 3);
            float d = sqrtf(fmaxf(m + sx2[i], 0.f));
            atomicMin(&sbm2[i], __float_as_uint(d));
        }
    }
    __syncthreads();

    float v = 0.f;
    if (tid < 128) {
        if (n1 > 0 && tid < n2) v += __uint_as_float(sbm1[tid]);
        if (n2 > 0 && tid < n1) v += __uint_as_float(sbm2[tid]);
    }
#pragma unroll
    for (int off = 32; off >= 1; off >>= 1) v += __shfl_down(v, off);
    if (lane == 0) swsum[wid] = v;
    __syncthreads();
    if (tid == 0) out[bid] = swsum[0] + swsum[1] + swsum[2] + swsum[3];
}

extern "C" void kernel_launch(void* const* d_in, const int* in_sizes, int n_in,
                              void* d_out, int out_size, void* d_ws, size_t ws_size,
                              hipStream_t stream) {
    const float* v1  = (const float*)d_in[0];
    const int*   sz1 = (const int*)d_in[1];
    const float* v2  = (const float*)d_in[2];
    const int*   sz2 = (const int*)d_in[3];
    float* out = (float*)d_out;
    (void)in_sizes; (void)n_in; (void)out_size; (void)ws_size;

    char* ws = (char*)d_ws;
    ushort_t* v1b = (ushort_t*)ws;                       // 2 MB
    ushort_t* v2b = (ushort_t*)(ws + (2u << 20));        // 2 MB
    float*    x2g = (float*)(ws + (4u << 20));           // 32 KB
    float*    y2g = x2g + 64 * 128;                      // 32 KB

    softhd_pre<<<dim3(1024), dim3(256), 0, stream>>>(v1, v2, v1b, v2b, x2g, y2g);
    softhd_mfma<<<dim3(4096), dim3(256), 0, stream>>>(v1b, v2b, x2g, y2g,
                                                      sz1, sz2, out);
}

// Round 5
// 36.547 us; speedup vs baseline: 77.2720x; 1.3632x over previous
//
#include <hip/hip_runtime.h>
#include <math.h>

// SoftHd via bf16 MFMA, K-split, merge-tree epilogue.
// out[b1,b2] = sum_{j<sz2} min_{i<sz1} dist[i,j] + sum_{i<sz1} min_{j<sz2} dist[i,j]
// dist via gemm identity on bf16-rounded inputs (MFMA 16x16x32_bf16).
// Epilogue: u = x2+y2-2xy per element (masking folded as +INF operands);
// both mins reduce u; sqrt AFTER reduction (monotone). Cross-lane mins via
// bitwise merge-reduce (acc bit k folded with lane bit k) so the final
// min lands on all 64 lanes with a distinct output index per lane.

typedef __attribute__((ext_vector_type(8))) short short8;
typedef __attribute__((ext_vector_type(4))) float f32x4;
typedef unsigned int u32;
typedef unsigned short ushort_t;

static __device__ __forceinline__ ushort_t f32_to_bf16_rne(float f) {
    u32 b = __float_as_uint(f);
    b += 0x7FFFu + ((b >> 16) & 1u);
    return (ushort_t)(b >> 16);
}

// ---------------------------------------------------------------------------
// Pre-kernel: f32 -> bf16 with per-row XOR chunk swizzle (16B chunk p = c ^
// (r&7)); XOR stays within each 8-chunk half so K-halves stay contiguous.
// Emits per-row squared norms (fp32 of the ROUNDED values).
// ---------------------------------------------------------------------------
__global__ __launch_bounds__(256) void softhd_pre(
    const float* __restrict__ v1, const float* __restrict__ v2,
    ushort_t* __restrict__ v1b, ushort_t* __restrict__ v2b,
    float* __restrict__ x2g, float* __restrict__ y2g)
{
    int flat = blockIdx.x * 256 + threadIdx.x;
    int c = flat & 15;
    int r = (flat >> 4) & 127;
    int b = (flat >> 11) & 63;
    int t = flat >> 17;

    const float* src = (t ? v2 : v1) + ((size_t)((b << 7) + r) << 7) + c * 8;
    ushort_t* dst = (t ? v2b : v1b) + ((size_t)((b << 7) + r) << 7);

    float4 q0 = *(const float4*)(src);
    float4 q1 = *(const float4*)(src + 4);

    ushort_t h[8];
    h[0] = f32_to_bf16_rne(q0.x); h[1] = f32_to_bf16_rne(q0.y);
    h[2] = f32_to_bf16_rne(q0.z); h[3] = f32_to_bf16_rne(q0.w);
    h[4] = f32_to_bf16_rne(q1.x); h[5] = f32_to_bf16_rne(q1.y);
    h[6] = f32_to_bf16_rne(q1.z); h[7] = f32_to_bf16_rne(q1.w);

    float p = 0.f;
#pragma unroll
    for (int k = 0; k < 8; ++k) {
        float fv = __uint_as_float((u32)h[k] << 16);
        p += fv * fv;
    }

    uint4 w;
    w.x = (u32)h[0] | ((u32)h[1] << 16);
    w.y = (u32)h[2] | ((u32)h[3] << 16);
    w.z = (u32)h[4] | ((u32)h[5] << 16);
    w.w = (u32)h[6] | ((u32)h[7] << 16);
    *(uint4*)(dst + ((c ^ (r & 7)) << 3)) = w;

    p += __shfl_xor(p, 1);
    p += __shfl_xor(p, 2);
    p += __shfl_xor(p, 4);
    p += __shfl_xor(p, 8);
    if (c == 0) (t ? y2g : x2g)[(b << 7) + r] = p;
}

// Stage one 64-col K-half of both panels (16KB each) via global_load_lds w=16.
static __device__ __forceinline__ void stage_half(
    const char* g1, const char* g2, ushort_t* s1, ushort_t* s2,
    int tid, int srcoff)
{
#pragma unroll
    for (int it = 0; it < 4; ++it) {
        int m = it * 256 + tid;                       // 16B-chunk idx, 0..1023
        int so = ((m >> 3) << 8) + srcoff + ((m & 7) << 4);
        int dof = m << 4;
        __builtin_amdgcn_global_load_lds(
            (const __attribute__((address_space(1))) u32*)(g1 + so),
            (__attribute__((address_space(3))) u32*)((char*)s1 + dof),
            16, 0, 0);
        __builtin_amdgcn_global_load_lds(
            (const __attribute__((address_space(1))) u32*)(g2 + so),
            (__attribute__((address_space(3))) u32*)((char*)s2 + dof),
            16, 0, 0);
    }
}

// ---------------------------------------------------------------------------
// Main kernel: one block per (b1,b2). 4 waves, 2x2 quadrant split (64x64 out
// per wave). K in 2 single-buffered halves -> ~35 KB LDS.
// ---------------------------------------------------------------------------
__global__ __launch_bounds__(256, 3) void softhd_mfma(
    const ushort_t* __restrict__ v1b, const ushort_t* __restrict__ v2b,
    const float* __restrict__ x2g, const float* __restrict__ y2g,
    const int* __restrict__ sz1, const int* __restrict__ sz2,
    float* __restrict__ out)
{
    __shared__ __align__(16) ushort_t s1[128 * 64];
    __shared__ __align__(16) ushort_t s2[128 * 64];
    __shared__ float sx2[128], sy2[128];
    __shared__ u32 sbm1[128], sbm2[128];
    __shared__ float swsum[4];

    const int tid = threadIdx.x;
    const int lane = tid & 63;
    const int wid = tid >> 6;
    // XCD-bijective swizzle (4096 % 8 == 0).
    const int bid = ((blockIdx.x & 7) << 9) | (blockIdx.x >> 3);
    const int b1 = bid >> 6, b2 = bid & 63;

    const char* g1 = (const char*)(v1b + ((size_t)b1 << 14));
    const char* g2 = (const char*)(v2b + ((size_t)b2 << 14));

    stage_half(g1, g2, s1, s2, tid, 0);

    if (tid < 128) {
        sx2[tid] = x2g[(b1 << 7) + tid];
        sbm1[tid] = 0x7F800000u;            // +inf bits
    } else {
        sy2[tid - 128] = y2g[(b2 << 7) + (tid - 128)];
        sbm2[tid - 128] = 0x7F800000u;
    }
    __syncthreads();

    const int qr = wid >> 1, qc = wid & 1;
    const int ibase = qr << 6, jbase = qc << 6;
    const int rf = lane & 15, kg = lane >> 4;
    const int h = rf & 7;

    const ushort_t* a_base = s1 + ((ibase + rf) << 6);   // row stride 64 elems
    const ushort_t* b_base = s2 + ((jbase + rf) << 6);

    f32x4 acc[4][4];
#pragma unroll
    for (int fi = 0; fi < 4; ++fi)
#pragma unroll
        for (int fj = 0; fj < 4; ++fj)
            acc[fi][fj] = (f32x4){0.f, 0.f, 0.f, 0.f};

#pragma unroll
    for (int half = 0; half < 2; ++half) {
        if (half == 1) {
            __syncthreads();                 // everyone done reading half 0
            stage_half(g1, g2, s1, s2, tid, 128);
            __syncthreads();                 // half 1 resident
        }
#pragma unroll
        for (int s = 0; s < 2; ++s) {
            const int p8 = (((s << 2) + kg) ^ h) << 3;
            short8 a[4], b[4];
#pragma unroll
            for (int f = 0; f < 4; ++f) {
                a[f] = *(const short8*)(a_base + (f << 10) + p8);
                b[f] = *(const short8*)(b_base + (f << 10) + p8);
            }
#pragma unroll
            for (int fi = 0; fi < 4; ++fi)
#pragma unroll
                for (int fj = 0; fj < 4; ++fj)
                    acc[fi][fj] = __builtin_amdgcn_mfma_f32_16x16x32_bf16(
                        a[fi], b[fj], acc[fi][fj], 0, 0, 0);
        }
    }

    const int n1 = min(max(sz1[b1], 0), 128);
    const int n2 = min(max(sz2[b2], 0), 128);
    const float INF = __builtin_inff();

    // Operand-folded masking: invalid rows/cols contribute +INF.
    float xie[16], yje[4];
#pragma unroll
    for (int t = 0; t < 16; ++t) {
        int i = ibase + ((t >> 2) << 4) + (kg << 2) + (t & 3);
        xie[t] = (i < n1) ? sx2[i] : INF;
    }
#pragma unroll
    for (int fj = 0; fj < 4; ++fj) {
        int j = jbase + (fj << 4) + rf;
        yje[fj] = (j < n2) ? sy2[j] : INF;
    }

    float minj[4], mini[16];
#pragma unroll
    for (int fj = 0; fj < 4; ++fj) minj[fj] = INF;
#pragma unroll
    for (int t = 0; t < 16; ++t) mini[t] = INF;

    // Element loop: u = full squared distance; min3-friendly accumulation.
#pragma unroll
    for (int fi = 0; fi < 4; ++fi) {
        float u[4][4];
#pragma unroll
        for (int fj = 0; fj < 4; ++fj)
#pragma unroll
            for (int q = 0; q < 4; ++q)
                u[fj][q] = fmaf(acc[fi][fj][q], -2.f, xie[fi * 4 + q] + yje[fj]);
#pragma unroll
        for (int fj = 0; fj < 4; ++fj) {
            minj[fj] = fminf(fminf(minj[fj], u[fj][0]), u[fj][1]);
            minj[fj] = fminf(fminf(minj[fj], u[fj][2]), u[fj][3]);
        }
#pragma unroll
        for (int q = 0; q < 4; ++q) {
            float mt = mini[fi * 4 + q];
            mt = fminf(fminf(mt, u[0][q]), u[1][q]);
            mt = fminf(fminf(mt, u[2][q]), u[3][q]);
            mini[fi * 4 + q] = mt;
        }
    }

    // Merge-reduce mini over rf lanes (acc bit k folded with lane bit k):
    // after 4 steps, mini[0] at lane (rf,kg) = min over all 64 j of the wave
    // quadrant, for i = ibase + (rf>>2)*16 + kg*4 + (rf&3).
#pragma unroll
    for (int k = 0; k < 4; ++k) {
        const int d = 1 << k;
        const bool hi = (lane >> k) & 1;
#pragma unroll
        for (int base = 0; base < 16; base += 2 * (1 << k)) {
            float pa = fminf(mini[base], __shfl_xor(mini[base], d));
            float pb = fminf(mini[base + d], __shfl_xor(mini[base + d], d));
            mini[base] = hi ? pb : pa;
        }
    }
    {
        float dmin = __builtin_amdgcn_sqrtf(fmaxf(mini[0], 0.f));
        int i = ibase + ((rf >> 2) << 4) + (kg << 2) + (rf & 3);
        atomicMin(&sbm2[i], __float_as_uint(dmin));
    }

    // Merge-reduce minj over kg lanes (acc bit k with lane bit 4+k):
    // after 2 steps, minj[0] at lane = min over all 64 i, for j = jbase+lane.
#pragma unroll
    for (int k = 0; k < 2; ++k) {
        const int d = 16 << k;
        const bool hi = (lane >> (4 + k)) & 1;
#pragma unroll
        for (int base = 0; base < 4; base += 2 * (1 << k)) {
            float pa = fminf(minj[base], __shfl_xor(minj[base], d));
            float pb = fminf(minj[base + (1 << k)],
                             __shfl_xor(minj[base + (1 << k)], d));
            minj[base] = hi ? pb : pa;
        }
    }
    {
        float dmin = __builtin_amdgcn_sqrtf(fmaxf(minj[0], 0.f));
        atomicMin(&sbm1[jbase + lane], __float_as_uint(dmin));
    }
    __syncthreads();

    float v = 0.f;
    if (tid < 128) {
        if (n1 > 0 && tid < n2) v += __uint_as_float(sbm1[tid]);
        if (n2 > 0 && tid < n1) v += __uint_as_float(sbm2[tid]);
    }
#pragma unroll
    for (int off = 32; off >= 1; off >>= 1) v += __shfl_down(v, off);
    if (lane == 0) swsum[wid] = v;
    __syncthreads();
    if (tid == 0) out[bid] = swsum[0] + swsum[1] + swsum[2] + swsum[3];
}

extern "C" void kernel_launch(void* const* d_in, const int* in_sizes, int n_in,
                              void* d_out, int out_size, void* d_ws, size_t ws_size,
                              hipStream_t stream) {
    const float* v1  = (const float*)d_in[0];
    const int*   sz1 = (const int*)d_in[1];
    const float* v2  = (const float*)d_in[2];
    const int*   sz2 = (const int*)d_in[3];
    float* out = (float*)d_out;
    (void)in_sizes; (void)n_in; (void)out_size; (void)ws_size;

    char* ws = (char*)d_ws;
    ushort_t* v1b = (ushort_t*)ws;                       // 2 MB
    ushort_t* v2b = (ushort_t*)(ws + (2u << 20));        // 2 MB
    float*    x2g = (float*)(ws + (4u << 20));           // 32 KB
    float*    y2g = x2g + 64 * 128;                      // 32 KB

    softhd_pre<<<dim3(1024), dim3(256), 0, stream>>>(v1, v2, v1b, v2b, x2g, y2g);
    softhd_mfma<<<dim3(4096), dim3(256), 0, stream>>>(v1b, v2b, x2g, y2g,
                                                      sz1, sz2, out);
}